// Round 6
// baseline (506.793 us; speedup 1.0000x reference)
//
#include <hip/hip_runtime.h>
#include <math.h>

// FATM spiking token mixer, MI355X (round 6: conv occupancy/latency fix).
// Shapes: T=4 B=8 C=512 H=W=32, nb=16 bs=32.
// Workspace layout (33,558,528 B, unchanged):
//   [0, 4096)            : Q (32x32 f32 Haar matrix, built on device)
//   [4096, +16777216)    : xs  spikes of LIF(x), u8, [T,B,C,H,W]
//   [.., +16777216)      : h1  spikes after Haar-fwd/NegIF/BN0/LIF, u8
// d_out doubles as the "mixed"/haar buffer between k_mix and k_conv_mfma.

#define T_    4
#define B_    8
#define C_    512
#define HW_   1024
#define CHW_  524288      // C_*HW_
#define BCHW_ 4194304     // B_*CHW_
#define NB_   16
#define EPS_  1e-5f
#define QSTR  36          // LDS row stride (floats) for 32-row f32 tiles

typedef _Float16 half8_t __attribute__((ext_vector_type(8)));
typedef float f32x16_t __attribute__((ext_vector_type(16)));

// ---------------------------------------------------------------- Q builder
__global__ void k_build_q(float* __restrict__ q) {
  int idx = threadIdx.x;            // 1024 threads
  int k = idx >> 5, j = idx & 31;
  double m = 1.0;
  if (k == 0) {
    for (int s = 0; s < 5; ++s) m /= sqrt(2.0);
    q[idx] = (float)m;
    return;
  }
  int p = 31 - __clz(k);            // floor(log2 k)
  for (int s = 0; s < 5 - p; ++s) m /= sqrt(2.0);
  int L = 32 >> p;
  int st = (k - (1 << p)) * L;
  int half = L >> 1;
  float v = 0.0f;
  if (j >= st && j < st + half)       v = (float)m;
  else if (j >= st + half && j < st + L) v = -(float)m;
  q[idx] = v;
}

// ---------------------------------------------------------------- LIF on x
__global__ __launch_bounds__(256) void k_lif_x(const float* __restrict__ x,
                                               unsigned char* __restrict__ xs) {
  size_t i4 = ((size_t)blockIdx.x * 256 + threadIdx.x) * 4;   // grid 4096
  float v[4] = {0.f, 0.f, 0.f, 0.f};
  for (int t = 0; t < T_; ++t) {
    float4 xv = *(const float4*)(x + (size_t)t * BCHW_ + i4);
    float xa[4] = {xv.x, xv.y, xv.z, xv.w};
    unsigned char sb[4];
#pragma unroll
    for (int e = 0; e < 4; ++e) {
      v[e] += (xa[e] - v[e]) * 0.5f;
      bool sp = v[e] >= 1.0f;
      sb[e] = sp ? 1 : 0;
      if (sp) v[e] = 0.0f;
    }
    uchar4 s; s.x = sb[0]; s.y = sb[1]; s.z = sb[2]; s.w = sb[3];
    *(uchar4*)(xs + (size_t)t * BCHW_ + i4) = s;
  }
}

// ------------------------------------------- Haar fwd + NegIF + BN0 + LIF
__global__ __launch_bounds__(256) void k_haar_fwd(
    const unsigned char* __restrict__ xs, const float* __restrict__ qg,
    const float* __restrict__ bnw, const float* __restrict__ bnb,
    const float* __restrict__ bnm, const float* __restrict__ bnv,
    unsigned char* __restrict__ h1) {
  __shared__ __align__(16) float QT[32 * QSTR];      // QT[j][i] = Q[i][j]
  __shared__ __align__(16) float Xs[4][32 * QSTR];
  __shared__ __align__(16) float Tt[4][32 * QSTR];   // Tt[k][i] = tmp[i][k]
  const int tid = threadIdx.x;
  for (int e2 = tid; e2 < 1024; e2 += 256) {
    int i = e2 >> 5, j = e2 & 31;
    QT[j * QSTR + i] = qg[e2];
  }
  const int im = tid >> 6;
  const int e  = tid & 63;
  const int i0 = (e >> 3) * 4;
  const int c0 = (e & 7) * 4;
  const int gc = blockIdx.x * 4 + im;      // b*512 + c
  const int c  = gc & 511;
  const float inv0 = bnw[c] / sqrtf(bnv[c] + EPS_);
  const float bet0 = __fsub_rn(bnb[c], __fmul_rn(bnm[c], inv0));
  const size_t base = (size_t)(gc >> 9) * CHW_ + (size_t)c * HW_;
  float vn[4][4], vl[4][4];
#pragma unroll
  for (int r = 0; r < 4; ++r)
#pragma unroll
    for (int q = 0; q < 4; ++q) { vn[r][q] = 0.f; vl[r][q] = 0.f; }
  __syncthreads();
  for (int t = 0; t < T_; ++t) {
    const uchar4* sp = (const uchar4*)(xs + (size_t)t * BCHW_ + base + e * 16);
#pragma unroll
    for (int q = 0; q < 4; ++q) {
      uchar4 s4 = sp[q];
      int px = e * 16 + q * 4;
      float4 f;
      f.x = (float)s4.x; f.y = (float)s4.y; f.z = (float)s4.z; f.w = (float)s4.w;
      *(float4*)&Xs[im][(px >> 5) * QSTR + (px & 31)] = f;
    }
    __syncthreads();
    float a[4][4];
#pragma unroll
    for (int r = 0; r < 4; ++r)
#pragma unroll
      for (int q = 0; q < 4; ++q) a[r][q] = 0.f;
    for (int j = 0; j < 32; ++j) {
      float4 qv = *(const float4*)&QT[j * QSTR + i0];
      float4 xv = *(const float4*)&Xs[im][j * QSTR + c0];
      float qa[4] = {qv.x, qv.y, qv.z, qv.w};
      float xa[4] = {xv.x, xv.y, xv.z, xv.w};
#pragma unroll
      for (int r = 0; r < 4; ++r)
#pragma unroll
        for (int q = 0; q < 4; ++q) a[r][q] = fmaf(qa[r], xa[q], a[r][q]);
    }
#pragma unroll
    for (int q = 0; q < 4; ++q) {
      float4 f; f.x = a[0][q]; f.y = a[1][q]; f.z = a[2][q]; f.w = a[3][q];
      *(float4*)&Tt[im][(c0 + q) * QSTR + i0] = f;
    }
    __syncthreads();
    float y[4][4];
#pragma unroll
    for (int r = 0; r < 4; ++r)
#pragma unroll
      for (int q = 0; q < 4; ++q) y[r][q] = 0.f;
    for (int k = 0; k < 32; ++k) {
      float4 tv = *(const float4*)&Tt[im][k * QSTR + i0];
      float4 qv = *(const float4*)&QT[k * QSTR + c0];
      float ta[4] = {tv.x, tv.y, tv.z, tv.w};
      float qa[4] = {qv.x, qv.y, qv.z, qv.w};
#pragma unroll
      for (int r = 0; r < 4; ++r)
#pragma unroll
        for (int q = 0; q < 4; ++q) y[r][q] = fmaf(ta[r], qa[q], y[r][q]);
    }
#pragma unroll
    for (int r = 0; r < 4; ++r) {
      unsigned char sb[4];
#pragma unroll
      for (int q = 0; q < 4; ++q) {
        vn[r][q] += y[r][q];
        float s = 0.f;
        if (vn[r][q] >= 1.0f) s = 1.0f;
        else if (vn[r][q] <= -1.0f) s = -1.0f;
        vn[r][q] -= s;
        float bv = __fadd_rn(__fmul_rn(s, inv0), bet0);
        vl[r][q] += (bv - vl[r][q]) * 0.5f;
        bool spk = vl[r][q] >= 1.0f;
        sb[q] = spk ? 1 : 0;
        if (spk) vl[r][q] = 0.f;
      }
      uchar4 so; so.x = sb[0]; so.y = sb[1]; so.z = sb[2]; so.w = sb[3];
      *(uchar4*)(h1 + (size_t)t * BCHW_ + base + (size_t)((i0 + r) * 32 + c0)) = so;
    }
  }
}

// ---------------------------------------- block-diag channel mix + BN1
__global__ __launch_bounds__(256) void k_mix(
    const unsigned char* __restrict__ h1, const float* __restrict__ hwt,
    const float* __restrict__ bnw, const float* __restrict__ bnb,
    const float* __restrict__ bnm, const float* __restrict__ bnv,
    float* __restrict__ outm) {
  __shared__ unsigned char S[32 * 1024];
  __shared__ float Wt[1024];
  const int n = blockIdx.x;       // T*B
  const int blk = blockIdx.y;     // nb
  const int tid = threadIdx.x;
  for (int e = tid; e < 1024; e += 256) Wt[e] = hwt[blk * 1024 + e];
  const uint4* src = (const uint4*)(h1 + (size_t)n * CHW_ + (size_t)blk * 32 * HW_);
  uint4* dst = (uint4*)S;
  for (int e = tid; e < 2048; e += 256) dst[e] = src[e];
  __syncthreads();
  const int p0 = tid * 4;
  for (int k = 0; k < 32; ++k) {
    const int c = blk * 32 + k;
    const float inv = bnw[C_ + c] / sqrtf(bnv[C_ + c] + EPS_);
    const float bet = __fsub_rn(bnb[C_ + c], __fmul_rn(bnm[C_ + c], inv));
    float a0 = 0.f, a1 = 0.f, a2 = 0.f, a3 = 0.f;
    for (int d = 0; d < 32; ++d) {
      const float w = Wt[d * 32 + k];                       // broadcast
      const unsigned int sp = *(const unsigned int*)(S + d * 1024 + p0);
      a0 = fmaf((float)(sp & 255u), w, a0);
      a1 = fmaf((float)((sp >> 8) & 255u), w, a1);
      a2 = fmaf((float)((sp >> 16) & 255u), w, a2);
      a3 = fmaf((float)((sp >> 24) & 255u), w, a3);
    }
    float4 o;
    o.x = __fadd_rn(__fmul_rn(a0, inv), bet);
    o.y = __fadd_rn(__fmul_rn(a1, inv), bet);
    o.z = __fadd_rn(__fmul_rn(a2, inv), bet);
    o.w = __fadd_rn(__fmul_rn(a3, inv), bet);
    *(float4*)(outm + (size_t)n * CHW_ + (size_t)c * HW_ + p0) = o;
  }
}

// ------------------------------------------- Haar inverse + NegIF + BN2
__global__ __launch_bounds__(256) void k_haar_inv(
    const float* __restrict__ qg,
    const float* __restrict__ bnw, const float* __restrict__ bnb,
    const float* __restrict__ bnm, const float* __restrict__ bnv,
    float* out) {
  __shared__ __align__(16) float Qn[32 * QSTR];      // row-major Q
  __shared__ __align__(16) float Xs[4][32 * QSTR];
  __shared__ __align__(16) float Tt[4][32 * QSTR];
  const int tid = threadIdx.x;
  for (int e2 = tid; e2 < 1024; e2 += 256) {
    int i = e2 >> 5, j = e2 & 31;
    Qn[i * QSTR + j] = qg[e2];
  }
  const int im = tid >> 6;
  const int e  = tid & 63;
  const int i0 = (e >> 3) * 4;
  const int c0 = (e & 7) * 4;
  const int gc = blockIdx.x * 4 + im;
  const int c  = gc & 511;
  const float inv2 = bnw[2 * C_ + c] / sqrtf(bnv[2 * C_ + c] + EPS_);
  const float bet2 = __fsub_rn(bnb[2 * C_ + c], __fmul_rn(bnm[2 * C_ + c], inv2));
  const size_t base = (size_t)(gc >> 9) * CHW_ + (size_t)c * HW_;
  float vn[4][4];
#pragma unroll
  for (int r = 0; r < 4; ++r)
#pragma unroll
    for (int q = 0; q < 4; ++q) vn[r][q] = 0.f;
  __syncthreads();
  for (int t = 0; t < T_; ++t) {
    const float4* sp = (const float4*)(out + (size_t)t * BCHW_ + base + e * 16);
#pragma unroll
    for (int q = 0; q < 4; ++q) {
      float4 f = sp[q];
      int px = e * 16 + q * 4;
      *(float4*)&Xs[im][(px >> 5) * QSTR + (px & 31)] = f;
    }
    __syncthreads();
    float a[4][4];
#pragma unroll
    for (int r = 0; r < 4; ++r)
#pragma unroll
      for (int q = 0; q < 4; ++q) a[r][q] = 0.f;
    for (int j = 0; j < 32; ++j) {
      float4 qv = *(const float4*)&Qn[j * QSTR + i0];     // Q[j][i0..3]
      float4 xv = *(const float4*)&Xs[im][j * QSTR + c0];
      float qa[4] = {qv.x, qv.y, qv.z, qv.w};
      float xa[4] = {xv.x, xv.y, xv.z, xv.w};
#pragma unroll
      for (int r = 0; r < 4; ++r)
#pragma unroll
        for (int q = 0; q < 4; ++q) a[r][q] = fmaf(qa[r], xa[q], a[r][q]);
    }
#pragma unroll
    for (int q = 0; q < 4; ++q) {
      float4 f; f.x = a[0][q]; f.y = a[1][q]; f.z = a[2][q]; f.w = a[3][q];
      *(float4*)&Tt[im][(c0 + q) * QSTR + i0] = f;
    }
    __syncthreads();
    float y[4][4];
#pragma unroll
    for (int r = 0; r < 4; ++r)
#pragma unroll
      for (int q = 0; q < 4; ++q) y[r][q] = 0.f;
    for (int k = 0; k < 32; ++k) {
      float4 tv = *(const float4*)&Tt[im][k * QSTR + i0];
      float4 qv = *(const float4*)&Qn[k * QSTR + c0];     // Q[k][c0..3]
      float ta[4] = {tv.x, tv.y, tv.z, tv.w};
      float qa[4] = {qv.x, qv.y, qv.z, qv.w};
#pragma unroll
      for (int r = 0; r < 4; ++r)
#pragma unroll
        for (int q = 0; q < 4; ++q) y[r][q] = fmaf(ta[r], qa[q], y[r][q]);
    }
#pragma unroll
    for (int r = 0; r < 4; ++r) {
      float res[4];
#pragma unroll
      for (int q = 0; q < 4; ++q) {
        vn[r][q] += y[r][q];
        float s = 0.f;
        if (vn[r][q] >= 1.0f) s = 1.0f;
        else if (vn[r][q] <= -1.0f) s = -1.0f;
        vn[r][q] -= s;
        res[q] = __fadd_rn(__fmul_rn(s, inv2), bet2);
      }
      float4 ov; ov.x = res[0]; ov.y = res[1]; ov.z = res[2]; ov.w = res[3];
      *(float4*)(out + (size_t)t * BCHW_ + base + (size_t)((i0 + r) * 32 + c0)) = ov;
    }
  }
}

// ---------------------- MFMA conv branch (1x1 + 3x3 grouped) + BN3/BN4 + add
// Round-6 restructure: z-split 4 (8 y-rows/block), LDS 27.2 KB (5 blk/CU),
// halo-only zeroing, epilogue loads prefetched before the MFMA loop.
// D-tile = 32 oc x 32 px (one image row), v_mfma_f32_32x32x16_f16.
// A = weights (m=oc, lane&31; k=(lane>>5)*8+j), B = spikes from transposed
// LDS tile [10 rows][34 px][32 ic] f16, pixel stride 80 B (16B aligned).
// D layout: col(px)=lane&31, row(oc)=(reg&3)+8*(reg>>2)+4*(lane>>5).
#define XSTR_ 80                 // bytes per pixel slot (32 f16 + 8 pad)
#define YSTR_ (34 * XSTR_)       // 2720
#define SROWS_ 10                // 8 output rows + 2 halo
__global__ __launch_bounds__(256, 3) void k_conv_mfma(
    const unsigned char* __restrict__ xs, const float* __restrict__ x,
    const float* __restrict__ w1, const float* __restrict__ b1,
    const float* __restrict__ w2, const float* __restrict__ b2,
    const float* __restrict__ bnw, const float* __restrict__ bnb,
    const float* __restrict__ bnm, const float* __restrict__ bnv,
    float* out) {
  __shared__ __align__(16) unsigned char S[SROWS_ * 34 * XSTR_];  // 27200 B
  const int tid = threadIdx.x;
  const int n = blockIdx.x, blk = blockIdx.y, y0 = blockIdx.z * 8;
  const int wv = tid >> 6, ln = tid & 63;
  // zero halo columns (px slots 0 and 33), 400 words total
  for (int e = tid; e < 400; e += 256) {
    int row = e / 40, rem = e % 40;
    int colbase = (rem < 20) ? 0 : 33 * XSTR_;
    ((unsigned int*)&S[row * YSTR_ + colbase])[rem % 20] = 0u;
  }
  // ---- stage spikes u8 -> f16, transposed to [row][px][ic]; OOB rows -> 0 ----
  {
    const int ic4 = ln >> 3, px4 = ln & 7;
    const size_t gb = (size_t)n * CHW_ + (size_t)(blk * 32 + ic4 * 4) * HW_;
    for (int row = wv; row < SROWS_; row += 4) {
      const int gy = y0 - 1 + row;
      const bool ok = (gy >= 0) && (gy <= 31);
      unsigned int d0 = 0u, d1 = 0u, d2 = 0u, d3 = 0u;
      if (ok) {
        const size_t rb = gb + (size_t)gy * 32 + px4 * 4;
        d0 = *(const unsigned int*)(xs + rb);
        d1 = *(const unsigned int*)(xs + rb + HW_);
        d2 = *(const unsigned int*)(xs + rb + 2 * HW_);
        d3 = *(const unsigned int*)(xs + rb + 3 * HW_);
      }
#pragma unroll
      for (int p = 0; p < 4; ++p) {
        unsigned int q = ((d0 >> (8 * p)) & 0xFFu)
                       | (((d1 >> (8 * p)) & 0xFFu) << 8)
                       | (((d2 >> (8 * p)) & 0xFFu) << 16)
                       | (((d3 >> (8 * p)) & 0xFFu) << 24);
        unsigned int lo = ((q & 0xFFu) | ((q & 0xFF00u) << 8)) * 0x3C00u;
        unsigned int hi = (((q >> 16) & 0xFFu) | (((q >> 16) & 0xFF00u) << 8)) * 0x3C00u;
        uint2 wv2; wv2.x = lo; wv2.y = hi;
        *(uint2*)&S[row * YSTR_ + (px4 * 4 + p + 1) * XSTR_ + ic4 * 8] = wv2;
      }
    }
  }
  // ---- per-wave A fragments (f16 weights) + epilogue params ----
  const int oc_a = ln & 31, hh = ln >> 5;
  half8_t A2[18], A1[2];
#pragma unroll
  for (int tap = 0; tap < 9; ++tap) {
#pragma unroll
    for (int kh = 0; kh < 2; ++kh) {
      half8_t a;
#pragma unroll
      for (int j = 0; j < 8; ++j) {
        int ic = kh * 16 + hh * 8 + j;
        a[j] = (_Float16)w2[(oc_a * 32 + ic) * 9 + tap];
      }
      A2[tap * 2 + kh] = a;
    }
  }
#pragma unroll
  for (int kh = 0; kh < 2; ++kh) {
    half8_t a;
#pragma unroll
    for (int j = 0; j < 8; ++j)
      a[j] = (_Float16)w1[oc_a * 32 + kh * 16 + hh * 8 + j];
    A1[kh] = a;
  }
  float p3[16], p4[16], pcc[16];
#pragma unroll
  for (int r = 0; r < 16; ++r) {
    const int oc = (r & 3) + 8 * (r >> 2) + 4 * hh;
    const int c = blk * 32 + oc;
    const float i3 = bnw[3 * C_ + c] / sqrtf(bnv[3 * C_ + c] + EPS_);
    const float e3 = __fsub_rn(bnb[3 * C_ + c], __fmul_rn(bnm[3 * C_ + c], i3));
    const float i4 = bnw[4 * C_ + c] / sqrtf(bnv[4 * C_ + c] + EPS_);
    const float e4 = __fsub_rn(bnb[4 * C_ + c], __fmul_rn(bnm[4 * C_ + c], i4));
    p3[r] = i3; p4[r] = i4;
    pcc[r] = __fadd_rn(__fadd_rn(__fmul_rn(b1[oc], i3), e3),
                       __fadd_rn(__fmul_rn(b2[oc], i4), e4));
  }
  __syncthreads();
  // ---- compute: wave handles 2 row-tiles ----
  const int px = ln & 31;
  for (int i = 0; i < 2; ++i) {
    const int ly = wv * 2 + i;
    const int y = y0 + ly;
    // prefetch epilogue operands so HBM latency hides under MFMA
    float hva[16], xva[16];
#pragma unroll
    for (int r = 0; r < 16; ++r) {
      const int oc = (r & 3) + 8 * (r >> 2) + 4 * hh;
      const size_t off = (size_t)n * CHW_ + (size_t)(blk * 32 + oc) * HW_
                       + (size_t)(y * 32 + px);
      hva[r] = out[off];
      xva[r] = x[off];
    }
    f32x16_t ac1, ac2;
#pragma unroll
    for (int r = 0; r < 16; ++r) { ac1[r] = 0.f; ac2[r] = 0.f; }
#pragma unroll
    for (int tap = 0; tap < 9; ++tap) {
      const int dy = tap / 3, dx = tap % 3;
#pragma unroll
      for (int kh = 0; kh < 2; ++kh) {
        half8_t b = *(const half8_t*)&S[(ly + dy) * YSTR_ + (px + dx) * XSTR_
                                        + kh * 32 + hh * 16];
        ac2 = __builtin_amdgcn_mfma_f32_32x32x16_f16(A2[tap * 2 + kh], b, ac2, 0, 0, 0);
        if (tap == 4)
          ac1 = __builtin_amdgcn_mfma_f32_32x32x16_f16(A1[kh], b, ac1, 0, 0, 0);
      }
    }
    // epilogue: out = haar(out) + BN3(conv1) + BN4(conv2) + x
#pragma unroll
    for (int r = 0; r < 16; ++r) {
      const int oc = (r & 3) + 8 * (r >> 2) + 4 * hh;
      const size_t off = (size_t)n * CHW_ + (size_t)(blk * 32 + oc) * HW_
                       + (size_t)(y * 32 + px);
      float t1 = __fadd_rn(hva[r], __fmul_rn(ac1[r], p3[r]));
      float t2 = __fadd_rn(t1, __fmul_rn(ac2[r], p4[r]));
      out[off] = __fadd_rn(__fadd_rn(t2, pcc[r]), xva[r]);
    }
  }
}

extern "C" void kernel_launch(void* const* d_in, const int* in_sizes, int n_in,
                              void* d_out, int out_size, void* d_ws, size_t ws_size,
                              hipStream_t stream) {
  (void)in_sizes; (void)n_in; (void)out_size; (void)ws_size;
  const float* x   = (const float*)d_in[0];
  const float* hwt = (const float*)d_in[1];
  const float* w1  = (const float*)d_in[2];
  const float* b1  = (const float*)d_in[3];
  const float* w2  = (const float*)d_in[4];
  const float* b2  = (const float*)d_in[5];
  const float* bnw = (const float*)d_in[6];
  const float* bnb = (const float*)d_in[7];
  const float* bnm = (const float*)d_in[8];
  const float* bnv = (const float*)d_in[9];
  float* out = (float*)d_out;

  float* qg = (float*)d_ws;
  unsigned char* xs = (unsigned char*)d_ws + 4096;
  unsigned char* h1 = xs + (size_t)T_ * BCHW_;

  k_build_q<<<1, 1024, 0, stream>>>(qg);
  k_lif_x<<<BCHW_ / 1024, 256, 0, stream>>>(x, xs);
  k_haar_fwd<<<(B_ * C_) / 4, 256, 0, stream>>>(xs, qg, bnw, bnb, bnm, bnv, h1);
  k_mix<<<dim3(T_ * B_, NB_), 256, 0, stream>>>(h1, hwt, bnw, bnb, bnm, bnv, out);
  k_haar_inv<<<(B_ * C_) / 4, 256, 0, stream>>>(qg, bnw, bnb, bnm, bnv, out);
  k_conv_mfma<<<dim3(T_ * B_, NB_, 4), 256, 0, stream>>>(xs, x, w1, b1, w2, b2,
                                                         bnw, bnb, bnm, bnv, out);
}

// Round 9
// 424.281 us; speedup vs baseline: 1.1945x; 1.1945x over previous
//
#include <hip/hip_runtime.h>
#include <math.h>

// FATM spiking token mixer, MI355X (round 7 resubmit: revert spill-inducers).
// r6 regression root-cause: __launch_bounds__(256,3) + hva/xva prefetch arrays
// -> VGPR cap 84, fragment spills to scratch (WRITE_SIZE 64->320 MB, 2x time).
// r7 = r6 structure (z4 split, SROWS=10, 27.2KB LDS, halo-only zeroing) with
// plain launch_bounds(256) and inline epilogue loads (r5 style).
// Shapes: T=4 B=8 C=512 H=W=32, nb=16 bs=32.
// Workspace layout (33,558,528 B, unchanged):
//   [0, 4096)            : Q (32x32 f32 Haar matrix, built on device)
//   [4096, +16777216)    : xs  spikes of LIF(x), u8, [T,B,C,H,W]
//   [.., +16777216)      : h1  spikes after Haar-fwd/NegIF/BN0/LIF, u8
// d_out doubles as the "mixed"/haar buffer between k_mix and k_conv_mfma.

#define T_    4
#define B_    8
#define C_    512
#define HW_   1024
#define CHW_  524288      // C_*HW_
#define BCHW_ 4194304     // B_*CHW_
#define NB_   16
#define EPS_  1e-5f
#define QSTR  36          // LDS row stride (floats) for 32-row f32 tiles

typedef _Float16 half8_t __attribute__((ext_vector_type(8)));
typedef float f32x16_t __attribute__((ext_vector_type(16)));

// ---------------------------------------------------------------- Q builder
__global__ void k_build_q(float* __restrict__ q) {
  int idx = threadIdx.x;            // 1024 threads
  int k = idx >> 5, j = idx & 31;
  double m = 1.0;
  if (k == 0) {
    for (int s = 0; s < 5; ++s) m /= sqrt(2.0);
    q[idx] = (float)m;
    return;
  }
  int p = 31 - __clz(k);            // floor(log2 k)
  for (int s = 0; s < 5 - p; ++s) m /= sqrt(2.0);
  int L = 32 >> p;
  int st = (k - (1 << p)) * L;
  int half = L >> 1;
  float v = 0.0f;
  if (j >= st && j < st + half)       v = (float)m;
  else if (j >= st + half && j < st + L) v = -(float)m;
  q[idx] = v;
}

// ---------------------------------------------------------------- LIF on x
__global__ __launch_bounds__(256) void k_lif_x(const float* __restrict__ x,
                                               unsigned char* __restrict__ xs) {
  size_t i4 = ((size_t)blockIdx.x * 256 + threadIdx.x) * 4;   // grid 4096
  float v[4] = {0.f, 0.f, 0.f, 0.f};
  for (int t = 0; t < T_; ++t) {
    float4 xv = *(const float4*)(x + (size_t)t * BCHW_ + i4);
    float xa[4] = {xv.x, xv.y, xv.z, xv.w};
    unsigned char sb[4];
#pragma unroll
    for (int e = 0; e < 4; ++e) {
      v[e] += (xa[e] - v[e]) * 0.5f;
      bool sp = v[e] >= 1.0f;
      sb[e] = sp ? 1 : 0;
      if (sp) v[e] = 0.0f;
    }
    uchar4 s; s.x = sb[0]; s.y = sb[1]; s.z = sb[2]; s.w = sb[3];
    *(uchar4*)(xs + (size_t)t * BCHW_ + i4) = s;
  }
}

// ------------------------------------------- Haar fwd + NegIF + BN0 + LIF
__global__ __launch_bounds__(256) void k_haar_fwd(
    const unsigned char* __restrict__ xs, const float* __restrict__ qg,
    const float* __restrict__ bnw, const float* __restrict__ bnb,
    const float* __restrict__ bnm, const float* __restrict__ bnv,
    unsigned char* __restrict__ h1) {
  __shared__ __align__(16) float QT[32 * QSTR];      // QT[j][i] = Q[i][j]
  __shared__ __align__(16) float Xs[4][32 * QSTR];
  __shared__ __align__(16) float Tt[4][32 * QSTR];   // Tt[k][i] = tmp[i][k]
  const int tid = threadIdx.x;
  for (int e2 = tid; e2 < 1024; e2 += 256) {
    int i = e2 >> 5, j = e2 & 31;
    QT[j * QSTR + i] = qg[e2];
  }
  const int im = tid >> 6;
  const int e  = tid & 63;
  const int i0 = (e >> 3) * 4;
  const int c0 = (e & 7) * 4;
  const int gc = blockIdx.x * 4 + im;      // b*512 + c
  const int c  = gc & 511;
  const float inv0 = bnw[c] / sqrtf(bnv[c] + EPS_);
  const float bet0 = __fsub_rn(bnb[c], __fmul_rn(bnm[c], inv0));
  const size_t base = (size_t)(gc >> 9) * CHW_ + (size_t)c * HW_;
  float vn[4][4], vl[4][4];
#pragma unroll
  for (int r = 0; r < 4; ++r)
#pragma unroll
    for (int q = 0; q < 4; ++q) { vn[r][q] = 0.f; vl[r][q] = 0.f; }
  __syncthreads();
  for (int t = 0; t < T_; ++t) {
    const uchar4* sp = (const uchar4*)(xs + (size_t)t * BCHW_ + base + e * 16);
#pragma unroll
    for (int q = 0; q < 4; ++q) {
      uchar4 s4 = sp[q];
      int px = e * 16 + q * 4;
      float4 f;
      f.x = (float)s4.x; f.y = (float)s4.y; f.z = (float)s4.z; f.w = (float)s4.w;
      *(float4*)&Xs[im][(px >> 5) * QSTR + (px & 31)] = f;
    }
    __syncthreads();
    float a[4][4];
#pragma unroll
    for (int r = 0; r < 4; ++r)
#pragma unroll
      for (int q = 0; q < 4; ++q) a[r][q] = 0.f;
    for (int j = 0; j < 32; ++j) {
      float4 qv = *(const float4*)&QT[j * QSTR + i0];
      float4 xv = *(const float4*)&Xs[im][j * QSTR + c0];
      float qa[4] = {qv.x, qv.y, qv.z, qv.w};
      float xa[4] = {xv.x, xv.y, xv.z, xv.w};
#pragma unroll
      for (int r = 0; r < 4; ++r)
#pragma unroll
        for (int q = 0; q < 4; ++q) a[r][q] = fmaf(qa[r], xa[q], a[r][q]);
    }
#pragma unroll
    for (int q = 0; q < 4; ++q) {
      float4 f; f.x = a[0][q]; f.y = a[1][q]; f.z = a[2][q]; f.w = a[3][q];
      *(float4*)&Tt[im][(c0 + q) * QSTR + i0] = f;
    }
    __syncthreads();
    float y[4][4];
#pragma unroll
    for (int r = 0; r < 4; ++r)
#pragma unroll
      for (int q = 0; q < 4; ++q) y[r][q] = 0.f;
    for (int k = 0; k < 32; ++k) {
      float4 tv = *(const float4*)&Tt[im][k * QSTR + i0];
      float4 qv = *(const float4*)&QT[k * QSTR + c0];
      float ta[4] = {tv.x, tv.y, tv.z, tv.w};
      float qa[4] = {qv.x, qv.y, qv.z, qv.w};
#pragma unroll
      for (int r = 0; r < 4; ++r)
#pragma unroll
        for (int q = 0; q < 4; ++q) y[r][q] = fmaf(ta[r], qa[q], y[r][q]);
    }
#pragma unroll
    for (int r = 0; r < 4; ++r) {
      unsigned char sb[4];
#pragma unroll
      for (int q = 0; q < 4; ++q) {
        vn[r][q] += y[r][q];
        float s = 0.f;
        if (vn[r][q] >= 1.0f) s = 1.0f;
        else if (vn[r][q] <= -1.0f) s = -1.0f;
        vn[r][q] -= s;
        float bv = __fadd_rn(__fmul_rn(s, inv0), bet0);
        vl[r][q] += (bv - vl[r][q]) * 0.5f;
        bool spk = vl[r][q] >= 1.0f;
        sb[q] = spk ? 1 : 0;
        if (spk) vl[r][q] = 0.f;
      }
      uchar4 so; so.x = sb[0]; so.y = sb[1]; so.z = sb[2]; so.w = sb[3];
      *(uchar4*)(h1 + (size_t)t * BCHW_ + base + (size_t)((i0 + r) * 32 + c0)) = so;
    }
  }
}

// ---------------------------------------- block-diag channel mix + BN1
__global__ __launch_bounds__(256) void k_mix(
    const unsigned char* __restrict__ h1, const float* __restrict__ hwt,
    const float* __restrict__ bnw, const float* __restrict__ bnb,
    const float* __restrict__ bnm, const float* __restrict__ bnv,
    float* __restrict__ outm) {
  __shared__ unsigned char S[32 * 1024];
  __shared__ float Wt[1024];
  const int n = blockIdx.x;       // T*B
  const int blk = blockIdx.y;     // nb
  const int tid = threadIdx.x;
  for (int e = tid; e < 1024; e += 256) Wt[e] = hwt[blk * 1024 + e];
  const uint4* src = (const uint4*)(h1 + (size_t)n * CHW_ + (size_t)blk * 32 * HW_);
  uint4* dst = (uint4*)S;
  for (int e = tid; e < 2048; e += 256) dst[e] = src[e];
  __syncthreads();
  const int p0 = tid * 4;
  for (int k = 0; k < 32; ++k) {
    const int c = blk * 32 + k;
    const float inv = bnw[C_ + c] / sqrtf(bnv[C_ + c] + EPS_);
    const float bet = __fsub_rn(bnb[C_ + c], __fmul_rn(bnm[C_ + c], inv));
    float a0 = 0.f, a1 = 0.f, a2 = 0.f, a3 = 0.f;
    for (int d = 0; d < 32; ++d) {
      const float w = Wt[d * 32 + k];                       // broadcast
      const unsigned int sp = *(const unsigned int*)(S + d * 1024 + p0);
      a0 = fmaf((float)(sp & 255u), w, a0);
      a1 = fmaf((float)((sp >> 8) & 255u), w, a1);
      a2 = fmaf((float)((sp >> 16) & 255u), w, a2);
      a3 = fmaf((float)((sp >> 24) & 255u), w, a3);
    }
    float4 o;
    o.x = __fadd_rn(__fmul_rn(a0, inv), bet);
    o.y = __fadd_rn(__fmul_rn(a1, inv), bet);
    o.z = __fadd_rn(__fmul_rn(a2, inv), bet);
    o.w = __fadd_rn(__fmul_rn(a3, inv), bet);
    *(float4*)(outm + (size_t)n * CHW_ + (size_t)c * HW_ + p0) = o;
  }
}

// ------------------------------------------- Haar inverse + NegIF + BN2
__global__ __launch_bounds__(256) void k_haar_inv(
    const float* __restrict__ qg,
    const float* __restrict__ bnw, const float* __restrict__ bnb,
    const float* __restrict__ bnm, const float* __restrict__ bnv,
    float* out) {
  __shared__ __align__(16) float Qn[32 * QSTR];      // row-major Q
  __shared__ __align__(16) float Xs[4][32 * QSTR];
  __shared__ __align__(16) float Tt[4][32 * QSTR];
  const int tid = threadIdx.x;
  for (int e2 = tid; e2 < 1024; e2 += 256) {
    int i = e2 >> 5, j = e2 & 31;
    Qn[i * QSTR + j] = qg[e2];
  }
  const int im = tid >> 6;
  const int e  = tid & 63;
  const int i0 = (e >> 3) * 4;
  const int c0 = (e & 7) * 4;
  const int gc = blockIdx.x * 4 + im;
  const int c  = gc & 511;
  const float inv2 = bnw[2 * C_ + c] / sqrtf(bnv[2 * C_ + c] + EPS_);
  const float bet2 = __fsub_rn(bnb[2 * C_ + c], __fmul_rn(bnm[2 * C_ + c], inv2));
  const size_t base = (size_t)(gc >> 9) * CHW_ + (size_t)c * HW_;
  float vn[4][4];
#pragma unroll
  for (int r = 0; r < 4; ++r)
#pragma unroll
    for (int q = 0; q < 4; ++q) vn[r][q] = 0.f;
  __syncthreads();
  for (int t = 0; t < T_; ++t) {
    const float4* sp = (const float4*)(out + (size_t)t * BCHW_ + base + e * 16);
#pragma unroll
    for (int q = 0; q < 4; ++q) {
      float4 f = sp[q];
      int px = e * 16 + q * 4;
      *(float4*)&Xs[im][(px >> 5) * QSTR + (px & 31)] = f;
    }
    __syncthreads();
    float a[4][4];
#pragma unroll
    for (int r = 0; r < 4; ++r)
#pragma unroll
      for (int q = 0; q < 4; ++q) a[r][q] = 0.f;
    for (int j = 0; j < 32; ++j) {
      float4 qv = *(const float4*)&Qn[j * QSTR + i0];     // Q[j][i0..3]
      float4 xv = *(const float4*)&Xs[im][j * QSTR + c0];
      float qa[4] = {qv.x, qv.y, qv.z, qv.w};
      float xa[4] = {xv.x, xv.y, xv.z, xv.w};
#pragma unroll
      for (int r = 0; r < 4; ++r)
#pragma unroll
        for (int q = 0; q < 4; ++q) a[r][q] = fmaf(qa[r], xa[q], a[r][q]);
    }
#pragma unroll
    for (int q = 0; q < 4; ++q) {
      float4 f; f.x = a[0][q]; f.y = a[1][q]; f.z = a[2][q]; f.w = a[3][q];
      *(float4*)&Tt[im][(c0 + q) * QSTR + i0] = f;
    }
    __syncthreads();
    float y[4][4];
#pragma unroll
    for (int r = 0; r < 4; ++r)
#pragma unroll
      for (int q = 0; q < 4; ++q) y[r][q] = 0.f;
    for (int k = 0; k < 32; ++k) {
      float4 tv = *(const float4*)&Tt[im][k * QSTR + i0];
      float4 qv = *(const float4*)&Qn[k * QSTR + c0];     // Q[k][c0..3]
      float ta[4] = {tv.x, tv.y, tv.z, tv.w};
      float qa[4] = {qv.x, qv.y, qv.z, qv.w};
#pragma unroll
      for (int r = 0; r < 4; ++r)
#pragma unroll
        for (int q = 0; q < 4; ++q) y[r][q] = fmaf(ta[r], qa[q], y[r][q]);
    }
#pragma unroll
    for (int r = 0; r < 4; ++r) {
      float res[4];
#pragma unroll
      for (int q = 0; q < 4; ++q) {
        vn[r][q] += y[r][q];
        float s = 0.f;
        if (vn[r][q] >= 1.0f) s = 1.0f;
        else if (vn[r][q] <= -1.0f) s = -1.0f;
        vn[r][q] -= s;
        res[q] = __fadd_rn(__fmul_rn(s, inv2), bet2);
      }
      float4 ov; ov.x = res[0]; ov.y = res[1]; ov.z = res[2]; ov.w = res[3];
      *(float4*)(out + (size_t)t * BCHW_ + base + (size_t)((i0 + r) * 32 + c0)) = ov;
    }
  }
}

// ---------------------- MFMA conv branch (1x1 + 3x3 grouped) + BN3/BN4 + add
// z-split 4 (8 y-rows/block), LDS 27.2 KB, halo-only zeroing; no minwaves
// bound, no epilogue prefetch arrays (both caused VGPR-cap spills in r6).
// D-tile = 32 oc x 32 px (one image row), v_mfma_f32_32x32x16_f16.
// A = weights (m=oc, lane&31; k=(lane>>5)*8+j), B = spikes from transposed
// LDS tile [10 rows][34 px][32 ic] f16, pixel stride 80 B (16B aligned).
// D layout: col(px)=lane&31, row(oc)=(reg&3)+8*(reg>>2)+4*(lane>>5).
#define XSTR_ 80                 // bytes per pixel slot (32 f16 + 8 pad)
#define YSTR_ (34 * XSTR_)       // 2720
#define SROWS_ 10                // 8 output rows + 2 halo
__global__ __launch_bounds__(256) void k_conv_mfma(
    const unsigned char* __restrict__ xs, const float* __restrict__ x,
    const float* __restrict__ w1, const float* __restrict__ b1,
    const float* __restrict__ w2, const float* __restrict__ b2,
    const float* __restrict__ bnw, const float* __restrict__ bnb,
    const float* __restrict__ bnm, const float* __restrict__ bnv,
    float* out) {
  __shared__ __align__(16) unsigned char S[SROWS_ * 34 * XSTR_];  // 27200 B
  const int tid = threadIdx.x;
  const int n = blockIdx.x, blk = blockIdx.y, y0 = blockIdx.z * 8;
  const int wv = tid >> 6, ln = tid & 63;
  // zero halo columns (px slots 0 and 33)
  for (int e = tid; e < 400; e += 256) {
    int row = e / 40, rem = e % 40;
    int colbase = (rem < 20) ? 0 : 33 * XSTR_;
    ((unsigned int*)&S[row * YSTR_ + colbase])[rem % 20] = 0u;
  }
  // ---- stage spikes u8 -> f16, transposed to [row][px][ic]; OOB rows -> 0 ----
  {
    const int ic4 = ln >> 3, px4 = ln & 7;
    const size_t gb = (size_t)n * CHW_ + (size_t)(blk * 32 + ic4 * 4) * HW_;
    for (int row = wv; row < SROWS_; row += 4) {
      const int gy = y0 - 1 + row;
      const bool ok = (gy >= 0) && (gy <= 31);
      unsigned int d0 = 0u, d1 = 0u, d2 = 0u, d3 = 0u;
      if (ok) {
        const size_t rb = gb + (size_t)gy * 32 + px4 * 4;
        d0 = *(const unsigned int*)(xs + rb);
        d1 = *(const unsigned int*)(xs + rb + HW_);
        d2 = *(const unsigned int*)(xs + rb + 2 * HW_);
        d3 = *(const unsigned int*)(xs + rb + 3 * HW_);
      }
#pragma unroll
      for (int p = 0; p < 4; ++p) {
        unsigned int q = ((d0 >> (8 * p)) & 0xFFu)
                       | (((d1 >> (8 * p)) & 0xFFu) << 8)
                       | (((d2 >> (8 * p)) & 0xFFu) << 16)
                       | (((d3 >> (8 * p)) & 0xFFu) << 24);
        unsigned int lo = ((q & 0xFFu) | ((q & 0xFF00u) << 8)) * 0x3C00u;
        unsigned int hi = (((q >> 16) & 0xFFu) | (((q >> 16) & 0xFF00u) << 8)) * 0x3C00u;
        uint2 wv2; wv2.x = lo; wv2.y = hi;
        *(uint2*)&S[row * YSTR_ + (px4 * 4 + p + 1) * XSTR_ + ic4 * 8] = wv2;
      }
    }
  }
  // ---- per-wave A fragments (f16 weights) + epilogue params ----
  const int oc_a = ln & 31, hh = ln >> 5;
  half8_t A2[18], A1[2];
#pragma unroll
  for (int tap = 0; tap < 9; ++tap) {
#pragma unroll
    for (int kh = 0; kh < 2; ++kh) {
      half8_t a;
#pragma unroll
      for (int j = 0; j < 8; ++j) {
        int ic = kh * 16 + hh * 8 + j;
        a[j] = (_Float16)w2[(oc_a * 32 + ic) * 9 + tap];
      }
      A2[tap * 2 + kh] = a;
    }
  }
#pragma unroll
  for (int kh = 0; kh < 2; ++kh) {
    half8_t a;
#pragma unroll
    for (int j = 0; j < 8; ++j)
      a[j] = (_Float16)w1[oc_a * 32 + kh * 16 + hh * 8 + j];
    A1[kh] = a;
  }
  float p3[16], p4[16], pcc[16];
#pragma unroll
  for (int r = 0; r < 16; ++r) {
    const int oc = (r & 3) + 8 * (r >> 2) + 4 * hh;
    const int c = blk * 32 + oc;
    const float i3 = bnw[3 * C_ + c] / sqrtf(bnv[3 * C_ + c] + EPS_);
    const float e3 = __fsub_rn(bnb[3 * C_ + c], __fmul_rn(bnm[3 * C_ + c], i3));
    const float i4 = bnw[4 * C_ + c] / sqrtf(bnv[4 * C_ + c] + EPS_);
    const float e4 = __fsub_rn(bnb[4 * C_ + c], __fmul_rn(bnm[4 * C_ + c], i4));
    p3[r] = i3; p4[r] = i4;
    pcc[r] = __fadd_rn(__fadd_rn(__fmul_rn(b1[oc], i3), e3),
                       __fadd_rn(__fmul_rn(b2[oc], i4), e4));
  }
  __syncthreads();
  // ---- compute: wave handles 2 row-tiles ----
  const int px = ln & 31;
  for (int i = 0; i < 2; ++i) {
    const int ly = wv * 2 + i;
    const int y = y0 + ly;
    f32x16_t ac1, ac2;
#pragma unroll
    for (int r = 0; r < 16; ++r) { ac1[r] = 0.f; ac2[r] = 0.f; }
#pragma unroll
    for (int tap = 0; tap < 9; ++tap) {
      const int dy = tap / 3, dx = tap % 3;
#pragma unroll
      for (int kh = 0; kh < 2; ++kh) {
        half8_t b = *(const half8_t*)&S[(ly + dy) * YSTR_ + (px + dx) * XSTR_
                                        + kh * 32 + hh * 16];
        ac2 = __builtin_amdgcn_mfma_f32_32x32x16_f16(A2[tap * 2 + kh], b, ac2, 0, 0, 0);
        if (tap == 4)
          ac1 = __builtin_amdgcn_mfma_f32_32x32x16_f16(A1[kh], b, ac1, 0, 0, 0);
      }
    }
    // epilogue: out = haar(out) + BN3(conv1) + BN4(conv2) + x
#pragma unroll
    for (int r = 0; r < 16; ++r) {
      const int oc = (r & 3) + 8 * (r >> 2) + 4 * hh;
      const size_t off = (size_t)n * CHW_ + (size_t)(blk * 32 + oc) * HW_
                       + (size_t)(y * 32 + px);
      const float hv = out[off];
      const float xv = x[off];
      float t1 = __fadd_rn(hv, __fmul_rn(ac1[r], p3[r]));
      float t2 = __fadd_rn(t1, __fmul_rn(ac2[r], p4[r]));
      out[off] = __fadd_rn(__fadd_rn(t2, pcc[r]), xv);
    }
  }
}

extern "C" void kernel_launch(void* const* d_in, const int* in_sizes, int n_in,
                              void* d_out, int out_size, void* d_ws, size_t ws_size,
                              hipStream_t stream) {
  (void)in_sizes; (void)n_in; (void)out_size; (void)ws_size;
  const float* x   = (const float*)d_in[0];
  const float* hwt = (const float*)d_in[1];
  const float* w1  = (const float*)d_in[2];
  const float* b1  = (const float*)d_in[3];
  const float* w2  = (const float*)d_in[4];
  const float* b2  = (const float*)d_in[5];
  const float* bnw = (const float*)d_in[6];
  const float* bnb = (const float*)d_in[7];
  const float* bnm = (const float*)d_in[8];
  const float* bnv = (const float*)d_in[9];
  float* out = (float*)d_out;

  float* qg = (float*)d_ws;
  unsigned char* xs = (unsigned char*)d_ws + 4096;
  unsigned char* h1 = xs + (size_t)T_ * BCHW_;

  k_build_q<<<1, 1024, 0, stream>>>(qg);
  k_lif_x<<<BCHW_ / 1024, 256, 0, stream>>>(x, xs);
  k_haar_fwd<<<(B_ * C_) / 4, 256, 0, stream>>>(xs, qg, bnw, bnb, bnm, bnv, h1);
  k_mix<<<dim3(T_ * B_, NB_), 256, 0, stream>>>(h1, hwt, bnw, bnb, bnm, bnv, out);
  k_haar_inv<<<(B_ * C_) / 4, 256, 0, stream>>>(qg, bnw, bnb, bnm, bnv, out);
  k_conv_mfma<<<dim3(T_ * B_, NB_, 4), 256, 0, stream>>>(xs, x, w1, b1, w2, b2,
                                                         bnw, bnb, bnm, bnv, out);
}